// Round 1
// baseline (1429.397 us; speedup 1.0000x reference)
//
#include <hip/hip_runtime.h>
#include <math.h>

#define NROWS 65536
#define KCODES 1024
#define DDIM 256
#define ND_TOT (NROWS * DDIM)

// ---------- ws layout (bytes) ----------
// [0,        262144)  int   idx[N]
// [262144,   266240)  int   counts[K]
// [266240,   266248)  float acc[2] {qsum, pdsum}
// [266248,   270344)  float sw[K]
// [270344,   532488)  float sx[N]

// ================= row sums of squares, numpy-pairwise emulation =================
__global__ __launch_bounds__(256) void vq_rowsq(const float* __restrict__ x,
                                                const float* __restrict__ w,
                                                float* __restrict__ sx,
                                                float* __restrict__ sw) {
#pragma clang fp contract(off)
  int r = blockIdx.x * 256 + threadIdx.x;
  const float* src;
  float* dst;
  if (r < NROWS) {
    src = x + (size_t)r * DDIM; dst = sx + r;
  } else {
    int k = r - NROWS;
    if (k >= KCODES) return;
    src = w + (size_t)k * DDIM; dst = sw + k;
  }
  // numpy pairwise_sum(256) = unrolled8(first 128) + unrolled8(second 128)
  float halves[2];
#pragma unroll
  for (int h = 0; h < 2; ++h) {
    const float* p = src + h * 128;
    float acc[8];
#pragma unroll
    for (int j = 0; j < 8; ++j) { float v = p[j]; acc[j] = v * v; }
    for (int i = 8; i < 128; i += 8) {
#pragma unroll
      for (int j = 0; j < 8; ++j) { float v = p[i + j]; float e = v * v; acc[j] = acc[j] + e; }
    }
    halves[h] = ((acc[0] + acc[1]) + (acc[2] + acc[3])) + ((acc[4] + acc[5]) + (acc[6] + acc[7]));
  }
  *dst = halves[0] + halves[1];
}

// ================= fused distances + argmin =================
#define TR 128
#define TC 128
#define DK 32
#define LSTR 132  // padded row stride (floats); keeps 16B alignment, spreads banks

__global__ __launch_bounds__(256) void vq_argmin(const float* __restrict__ x,
                                                 const float* __restrict__ w,
                                                 const float* __restrict__ sx,
                                                 const float* __restrict__ sw,
                                                 float* __restrict__ idxOutF,
                                                 int* __restrict__ idxOutI) {
  __shared__ float xs[DK][LSTR];
  __shared__ float wl[DK][LSTR];
  __shared__ float sxs[TR];
  __shared__ float sws[TC];
  __shared__ float redD[16][TR];
  __shared__ int   redI[16][TR];

  const int t = threadIdx.x;
  const int tx = t & 15, ty = t >> 4;
  const int tx4 = tx * 4, ty4 = ty * 4;
  const int row0 = blockIdx.x * TR;

  if (t < TR) sxs[t] = sx[row0 + t];

  float bd[8];
  int bi[8];
#pragma unroll
  for (int u = 0; u < 8; ++u) { bd[u] = 3.4e38f; bi[u] = 0; }

  for (int kt = 0; kt < KCODES / TC; ++kt) {
    const int c0 = kt * TC;
    __syncthreads();            // protect sws/LDS from previous iteration's readers
    if (t < TC) sws[t] = sw[c0 + t];

    float acc[8][8];
#pragma unroll
    for (int u = 0; u < 8; ++u)
#pragma unroll
      for (int v = 0; v < 8; ++v) acc[u][v] = 0.f;

    for (int dt = 0; dt < DDIM; dt += DK) {
      __syncthreads();
#pragma unroll
      for (int it = 0; it < 4; ++it) {
        int q = it * 256 + t;
        int rr = q >> 3, db = (q & 7) * 4;
        float4 xv = *(const float4*)&x[(size_t)(row0 + rr) * DDIM + dt + db];
        xs[db + 0][rr] = xv.x; xs[db + 1][rr] = xv.y;
        xs[db + 2][rr] = xv.z; xs[db + 3][rr] = xv.w;
        float4 wv = *(const float4*)&w[(size_t)(c0 + rr) * DDIM + dt + db];
        wl[db + 0][rr] = wv.x; wl[db + 1][rr] = wv.y;
        wl[db + 2][rr] = wv.z; wl[db + 3][rr] = wv.w;
      }
      __syncthreads();
#pragma unroll 4
      for (int d = 0; d < DK; ++d) {
        const float4 xa = *(const float4*)&xs[d][ty4];
        const float4 xb = *(const float4*)&xs[d][ty4 + 64];
        const float4 wa = *(const float4*)&wl[d][tx4];
        const float4 wb = *(const float4*)&wl[d][tx4 + 64];
        float xr[8] = {xa.x, xa.y, xa.z, xa.w, xb.x, xb.y, xb.z, xb.w};
        float wc[8] = {wa.x, wa.y, wa.z, wa.w, wb.x, wb.y, wb.z, wb.w};
#pragma unroll
        for (int u = 0; u < 8; ++u)
#pragma unroll
          for (int v = 0; v < 8; ++v) acc[u][v] += xr[u] * wc[v];
      }
    }

    // scores: dist = fl(fl(sx+sw) - 2*dot), fp32, scan codes ascending (first-min wins)
#pragma unroll
    for (int u = 0; u < 8; ++u) {
      int rl = (u < 4) ? (ty4 + u) : (64 + ty4 + (u - 4));
      float sxv = sxs[rl];
#pragma unroll
      for (int v = 0; v < 8; ++v) {
        int cl = (v < 4) ? (tx4 + v) : (64 + tx4 + (v - 4));
        float t1 = sxv + sws[cl];
        float dist = t1 - 2.0f * acc[u][v];  // == t1 - fl(2*acc): 2*acc exact
        if (dist < bd[u]) { bd[u] = dist; bi[u] = c0 + cl; }
      }
    }
  }

  __syncthreads();
#pragma unroll
  for (int u = 0; u < 8; ++u) {
    int rl = (u < 4) ? (ty4 + u) : (64 + ty4 + (u - 4));
    redD[tx][rl] = bd[u];
    redI[tx][rl] = bi[u];
  }
  __syncthreads();
  if (t < TR) {
    float bD = redD[0][t]; int bI = redI[0][t];
#pragma unroll
    for (int j = 1; j < 16; ++j) {
      float dd = redD[j][t]; int ii = redI[j][t];
      if (dd < bD || (dd == bD && ii < bI)) { bD = dd; bI = ii; }
    }
    idxOutF[row0 + t] = (float)bI;
    idxOutI[row0 + t] = bI;
  }
}

// ================= gather + straight-through out + qloss + histogram =================
__global__ __launch_bounds__(256) void vq_quantize(const float* __restrict__ x,
                                                   const float* __restrict__ w,
                                                   const int* __restrict__ idxArr,
                                                   float* __restrict__ qout,
                                                   int* __restrict__ counts,
                                                   float* __restrict__ accQ) {
  int gw = (blockIdx.x * 256 + threadIdx.x) >> 6;  // one wave per row
  int lane = threadIdx.x & 63;
  int idx = idxArr[gw];
  const float4* xr = (const float4*)(x + (size_t)gw * DDIM);
  const float4* wr = (const float4*)(w + (size_t)idx * DDIM);
  float4 xv = xr[lane];
  float4 qv = wr[lane];
  float dx = qv.x - xv.x, dy = qv.y - xv.y, dz = qv.z - xv.z, dw = qv.w - xv.w;
  float4 o;
  o.x = xv.x + dx; o.y = xv.y + dy; o.z = xv.z + dz; o.w = xv.w + dw;  // x + (q - x), fp32 emulation
  ((float4*)(qout + (size_t)gw * DDIM))[lane] = o;
  double s = (double)(dx * dx) + (double)(dy * dy) + (double)(dz * dz) + (double)(dw * dw);
  for (int off = 32; off > 0; off >>= 1) s += __shfl_down(s, off);
  if (lane == 0) {
    atomicAdd(&counts[idx], 1);
    atomicAdd(accQ, (float)s);
  }
}

// ================= util loss =================
__global__ __launch_bounds__(1024) void vq_util(const int* __restrict__ counts,
                                                float* __restrict__ outp) {
  int t = threadIdx.x;  // 1024 threads, one per code
  float v = fabsf((float)counts[t] - 64.0f);
  for (int off = 32; off > 0; off >>= 1) v += __shfl_down(v, off);
  __shared__ float red[16];
  if ((t & 63) == 0) red[t >> 6] = v;
  __syncthreads();
  if (t == 0) {
    float s2 = 0.f;
    for (int j2 = 0; j2 < 16; ++j2) s2 += red[j2];
    outp[0] = s2 * (1.0f / 1024.0f);
  }
}

// ================= compactness: pairwise codebook distances =================
__global__ __launch_bounds__(256) void vq_compact(const float* __restrict__ w,
                                                  const float* __restrict__ sw,
                                                  float* __restrict__ accP) {
  const int i = blockIdx.x;
  const int t = threadIdx.x;
  __shared__ float wi[DDIM];
  wi[t] = w[(size_t)i * DDIM + t];
  __syncthreads();
  float swi = sw[i];
  double s = 0.0;
  for (int j = i + 1 + t; j < KCODES; j += 256) {
    const float4* wj = (const float4*)(w + (size_t)j * DDIM);
    const float4* wi4 = (const float4*)wi;
    float acc = 0.f;
#pragma unroll 8
    for (int d4 = 0; d4 < DDIM / 4; ++d4) {
      float4 a = wi4[d4];
      float4 b = wj[d4];
      acc += a.x * b.x + a.y * b.y + a.z * b.z + a.w * b.w;
    }
    float pd2 = (swi + sw[j]) - 2.0f * acc;
    s += (double)sqrtf(fmaxf(pd2, 1e-12f));
  }
  for (int off = 32; off > 0; off >>= 1) s += __shfl_down(s, off);
  __shared__ double red[4];
  if ((t & 63) == 0) red[t >> 6] = s;
  __syncthreads();
  if (t == 0) {
    double tot = red[0] + red[1] + red[2] + red[3];
    atomicAdd(accP, (float)tot);
  }
}

// ================= finalize scalars =================
__global__ void vq_finalize(const float* __restrict__ acc2, float* __restrict__ out) {
  if (threadIdx.x == 0 && blockIdx.x == 0) {
    float m = acc2[0] / 16777216.0f;      // q_latent == e_latent == mean((q-x)^2)
    out[ND_TOT] = m + 0.25f * m;          // quant_loss
    out[ND_TOT + 2] = 2.0f * acc2[1] / 523776.0f;  // compact_loss, n_pairs = K*(K-1)/2
  }
}

extern "C" void kernel_launch(void* const* d_in, const int* in_sizes, int n_in,
                              void* d_out, int out_size, void* d_ws, size_t ws_size,
                              hipStream_t stream) {
  const float* x = (const float*)d_in[0];
  const float* w = (const float*)d_in[1];
  float* out = (float*)d_out;

  char* ws = (char*)d_ws;
  int* wsIdx   = (int*)ws;
  int* counts  = (int*)(ws + 262144);
  float* acc2  = (float*)(ws + 266240);  // {qsum, pdsum}
  float* swv   = (float*)(ws + 266248);
  float* sxv   = (float*)(ws + 270344);

  // zero counts + the two accumulators
  hipMemsetAsync(ws + 262144, 0, 4096 + 8, stream);

  vq_rowsq<<<(NROWS + KCODES + 255) / 256, 256, 0, stream>>>(x, w, sxv, swv);
  vq_argmin<<<NROWS / TR, 256, 0, stream>>>(x, w, sxv, swv, out + ND_TOT + 3, wsIdx);
  vq_quantize<<<NROWS / 4, 256, 0, stream>>>(x, w, wsIdx, out, counts, acc2);
  vq_util<<<1, 1024, 0, stream>>>(counts, out + ND_TOT + 1);
  vq_compact<<<KCODES, 256, 0, stream>>>(w, swv, acc2 + 1);
  vq_finalize<<<1, 64, 0, stream>>>(acc2, out);
}

// Round 2
// 605.746 us; speedup vs baseline: 2.3597x; 2.3597x over previous
//
#include <hip/hip_runtime.h>
#include <math.h>

#define NROWS 65536
#define KCODES 1024
#define DDIM 256
#define ND_TOT (NROWS * DDIM)

// ---------- ws layout (bytes) ----------
// [0,       262144)  int    idx[N]
// [262144,  266240)  int    counts[K]
// [266240,  266248)  (unused pad)
// [266248,  270344)  float  sw[K]
// [270344,  532488)  float  sx[N]
// [532488,  536584)  float  partialQ[1024]
// [536584,  540680)  float  partialP[1024]

// ================= row sums of squares, numpy-pairwise emulation =================
__global__ __launch_bounds__(256) void vq_rowsq(const float* __restrict__ x,
                                                const float* __restrict__ w,
                                                float* __restrict__ sx,
                                                float* __restrict__ sw) {
#pragma clang fp contract(off)
  int r = blockIdx.x * 256 + threadIdx.x;
  const float* src;
  float* dst;
  if (r < NROWS) {
    src = x + (size_t)r * DDIM; dst = sx + r;
  } else {
    int k = r - NROWS;
    if (k >= KCODES) return;
    src = w + (size_t)k * DDIM; dst = sw + k;
  }
  // numpy pairwise_sum(256) = unrolled8(first 128) + unrolled8(second 128)
  float halves[2];
#pragma unroll
  for (int h = 0; h < 2; ++h) {
    const float* p = src + h * 128;
    float acc[8];
#pragma unroll
    for (int j = 0; j < 8; ++j) { float v = p[j]; acc[j] = v * v; }
    for (int i = 8; i < 128; i += 8) {
#pragma unroll
      for (int j = 0; j < 8; ++j) { float v = p[i + j]; float e = v * v; acc[j] = acc[j] + e; }
    }
    halves[h] = ((acc[0] + acc[1]) + (acc[2] + acc[3])) + ((acc[4] + acc[5]) + (acc[6] + acc[7]));
  }
  *dst = halves[0] + halves[1];
}

// ================= fused distances + argmin =================
#define TR 128
#define TC 128
#define DK 32
#define LSTR 132  // padded row stride (floats)

__global__ __launch_bounds__(256) void vq_argmin(const float* __restrict__ x,
                                                 const float* __restrict__ w,
                                                 const float* __restrict__ sx,
                                                 const float* __restrict__ sw,
                                                 float* __restrict__ idxOutF,
                                                 int* __restrict__ idxOutI) {
  __shared__ float xs[DK][LSTR];
  __shared__ float wl[DK][LSTR];
  __shared__ float sxs[TR];
  __shared__ float sws[TC];
  __shared__ float redD[16][TR];
  __shared__ int   redI[16][TR];

  const int t = threadIdx.x;
  const int tx = t & 15, ty = t >> 4;
  const int tx4 = tx * 4, ty4 = ty * 4;
  const int row0 = blockIdx.x * TR;

  if (t < TR) sxs[t] = sx[row0 + t];

  float bd[8];
  int bi[8];
#pragma unroll
  for (int u = 0; u < 8; ++u) { bd[u] = 3.4e38f; bi[u] = 0; }

  for (int kt = 0; kt < KCODES / TC; ++kt) {
    const int c0 = kt * TC;
    __syncthreads();
    if (t < TC) sws[t] = sw[c0 + t];

    float acc[8][8];
#pragma unroll
    for (int u = 0; u < 8; ++u)
#pragma unroll
      for (int v = 0; v < 8; ++v) acc[u][v] = 0.f;

    for (int dt = 0; dt < DDIM; dt += DK) {
      __syncthreads();
#pragma unroll
      for (int it = 0; it < 4; ++it) {
        int q = it * 256 + t;
        int rr = q >> 3, db = (q & 7) * 4;
        float4 xv = *(const float4*)&x[(size_t)(row0 + rr) * DDIM + dt + db];
        xs[db + 0][rr] = xv.x; xs[db + 1][rr] = xv.y;
        xs[db + 2][rr] = xv.z; xs[db + 3][rr] = xv.w;
        float4 wv = *(const float4*)&w[(size_t)(c0 + rr) * DDIM + dt + db];
        wl[db + 0][rr] = wv.x; wl[db + 1][rr] = wv.y;
        wl[db + 2][rr] = wv.z; wl[db + 3][rr] = wv.w;
      }
      __syncthreads();
#pragma unroll 4
      for (int d = 0; d < DK; ++d) {
        const float4 xa = *(const float4*)&xs[d][ty4];
        const float4 xb = *(const float4*)&xs[d][ty4 + 64];
        const float4 wa = *(const float4*)&wl[d][tx4];
        const float4 wb = *(const float4*)&wl[d][tx4 + 64];
        float xr[8] = {xa.x, xa.y, xa.z, xa.w, xb.x, xb.y, xb.z, xb.w};
        float wc[8] = {wa.x, wa.y, wa.z, wa.w, wb.x, wb.y, wb.z, wb.w};
#pragma unroll
        for (int u = 0; u < 8; ++u)
#pragma unroll
          for (int v = 0; v < 8; ++v) acc[u][v] += xr[u] * wc[v];
      }
    }

    // dist = fl(fl(sx+sw) - 2*dot), fp32, codes scanned ascending (first-min wins)
#pragma unroll
    for (int u = 0; u < 8; ++u) {
      int rl = (u < 4) ? (ty4 + u) : (64 + ty4 + (u - 4));
      float sxv = sxs[rl];
#pragma unroll
      for (int v = 0; v < 8; ++v) {
        int cl = (v < 4) ? (tx4 + v) : (64 + tx4 + (v - 4));
        float t1 = sxv + sws[cl];
        float dist = t1 - 2.0f * acc[u][v];
        if (dist < bd[u]) { bd[u] = dist; bi[u] = c0 + cl; }
      }
    }
  }

  __syncthreads();
#pragma unroll
  for (int u = 0; u < 8; ++u) {
    int rl = (u < 4) ? (ty4 + u) : (64 + ty4 + (u - 4));
    redD[tx][rl] = bd[u];
    redI[tx][rl] = bi[u];
  }
  __syncthreads();
  if (t < TR) {
    float bD = redD[0][t]; int bI = redI[0][t];
#pragma unroll
    for (int j = 1; j < 16; ++j) {
      float dd = redD[j][t]; int ii = redI[j][t];
      if (dd < bD || (dd == bD && ii < bI)) { bD = dd; bI = ii; }
    }
    idxOutF[row0 + t] = (float)bI;
    idxOutI[row0 + t] = bI;
  }
}

// ====== gather + straight-through out + qloss partial + histogram (no hot atomics) ======
// 1024 blocks x 256 threads; block = 4 waves; wave handles 16 rows.
__global__ __launch_bounds__(256) void vq_quantize(const float* __restrict__ x,
                                                   const float* __restrict__ w,
                                                   const int* __restrict__ idxArr,
                                                   float* __restrict__ qout,
                                                   int* __restrict__ counts,
                                                   float* __restrict__ partialQ) {
  const int wave = threadIdx.x >> 6;
  const int lane = threadIdx.x & 63;
  const int base = blockIdx.x * 64 + wave * 16;
  float s = 0.f;
#pragma unroll 4
  for (int r = 0; r < 16; ++r) {
    const int row = base + r;
    const int idx = idxArr[row];
    float4 xv = ((const float4*)(x + (size_t)row * DDIM))[lane];
    float4 qv = ((const float4*)(w + (size_t)idx * DDIM))[lane];
    float dx = qv.x - xv.x, dy = qv.y - xv.y, dz = qv.z - xv.z, dw = qv.w - xv.w;
    float4 o;
    o.x = xv.x + dx; o.y = xv.y + dy; o.z = xv.z + dz; o.w = xv.w + dw;  // x + (q - x)
    ((float4*)(qout + (size_t)row * DDIM))[lane] = o;
    s += dx * dx + dy * dy + dz * dz + dw * dw;
    if (lane == 0) atomicAdd(&counts[idx], 1);  // 1024 spread addresses — cheap
  }
  double d = s;
  for (int off = 32; off > 0; off >>= 1) d += __shfl_down(d, off);
  __shared__ double red[4];
  if (lane == 0) red[wave] = d;
  __syncthreads();
  if (threadIdx.x == 0)
    partialQ[blockIdx.x] = (float)(red[0] + red[1] + red[2] + red[3]);
}

// ================= compactness: pairwise codebook distances =================
__global__ __launch_bounds__(256) void vq_compact(const float* __restrict__ w,
                                                  const float* __restrict__ sw,
                                                  float* __restrict__ partialP) {
  const int i = blockIdx.x;
  const int t = threadIdx.x;
  __shared__ float wi[DDIM];
  wi[t] = w[(size_t)i * DDIM + t];
  __syncthreads();
  float swi = sw[i];
  double s = 0.0;
  for (int j = i + 1 + t; j < KCODES; j += 256) {
    const float4* wj = (const float4*)(w + (size_t)j * DDIM);
    const float4* wi4 = (const float4*)wi;
    float acc = 0.f;
#pragma unroll 8
    for (int d4 = 0; d4 < DDIM / 4; ++d4) {
      float4 a = wi4[d4];
      float4 b = wj[d4];
      acc += a.x * b.x + a.y * b.y + a.z * b.z + a.w * b.w;
    }
    float pd2 = (swi + sw[j]) - 2.0f * acc;
    s += (double)sqrtf(fmaxf(pd2, 1e-12f));
  }
  for (int off = 32; off > 0; off >>= 1) s += __shfl_down(s, off);
  __shared__ double red[4];
  if ((t & 63) == 0) red[t >> 6] = s;
  __syncthreads();
  if (t == 0)
    partialP[i] = (float)(red[0] + red[1] + red[2] + red[3]);
}

// ========== finalize: qloss reduce + util + compact reduce, one block ==========
__global__ __launch_bounds__(1024) void vq_final(const float* __restrict__ partialQ,
                                                 const float* __restrict__ partialP,
                                                 const int* __restrict__ counts,
                                                 float* __restrict__ out) {
  const int t = threadIdx.x;           // 1024 threads, 16 waves
  const int lane = t & 63, wave = t >> 6;
  double q = (double)partialQ[t];
  double p = (double)partialP[t];
  double u = (double)fabsf((float)counts[t] - 64.0f);
  for (int off = 32; off > 0; off >>= 1) {
    q += __shfl_down(q, off);
    p += __shfl_down(p, off);
    u += __shfl_down(u, off);
  }
  __shared__ double redQ[16], redP[16], redU[16];
  if (lane == 0) { redQ[wave] = q; redP[wave] = p; redU[wave] = u; }
  __syncthreads();
  if (t == 0) {
    double sq = 0, sp = 0, su = 0;
    for (int j = 0; j < 16; ++j) { sq += redQ[j]; sp += redP[j]; su += redU[j]; }
    float m = (float)(sq / 16777216.0);          // mean((q-x)^2)
    out[ND_TOT]     = m + 0.25f * m;             // quant_loss
    out[ND_TOT + 1] = (float)(su / 1024.0);      // util_loss
    out[ND_TOT + 2] = (float)(2.0 * sp / 523776.0);  // compact_loss
  }
}

extern "C" void kernel_launch(void* const* d_in, const int* in_sizes, int n_in,
                              void* d_out, int out_size, void* d_ws, size_t ws_size,
                              hipStream_t stream) {
  const float* x = (const float*)d_in[0];
  const float* w = (const float*)d_in[1];
  float* out = (float*)d_out;

  char* ws = (char*)d_ws;
  int* wsIdx     = (int*)ws;
  int* counts    = (int*)(ws + 262144);
  float* swv     = (float*)(ws + 266248);
  float* sxv     = (float*)(ws + 270344);
  float* partQ   = (float*)(ws + 532488);
  float* partP   = (float*)(ws + 536584);

  hipMemsetAsync(ws + 262144, 0, 4096, stream);  // counts only

  vq_rowsq<<<(NROWS + KCODES + 255) / 256, 256, 0, stream>>>(x, w, sxv, swv);
  vq_argmin<<<NROWS / TR, 256, 0, stream>>>(x, w, sxv, swv, out + ND_TOT + 3, wsIdx);
  vq_quantize<<<1024, 256, 0, stream>>>(x, w, wsIdx, out, counts, partQ);
  vq_compact<<<KCODES, 256, 0, stream>>>(w, swv, partP);
  vq_final<<<1, 1024, 0, stream>>>(partQ, partP, counts, out);
}

// Round 4
// 605.630 us; speedup vs baseline: 2.3602x; 1.0002x over previous
//
#include <hip/hip_runtime.h>
#include <math.h>

#define NROWS 65536
#define KCODES 1024
#define DDIM 256
#define ND_TOT (NROWS * DDIM)

// ---------- ws layout (bytes) ----------
#define WS_IDX      0         // int idx[N]          256KB
#define WS_COUNTS   262144    // int counts[K]       4KB
#define WS_SW       266240    // float sw[K]         4KB
#define WS_SX       270336    // float sx[N]         256KB
#define WS_PARTQ    532480    // float partQ[1024]   4KB
#define WS_PARTP    536576    // float partP[1024]   4KB
#define WS_FLAGCNT  540672    // int                 (256B slot)
#define WS_FLAGLIST 540928    // int flagList[N]     256KB
#define WS_WH       803072    // ushort wh[K*256]    512KB
#define WS_WL       1327360   // ushort wl[K*256]    512KB

typedef float f32x4 __attribute__((ext_vector_type(4)));
typedef short bf16x8 __attribute__((ext_vector_type(8)));

__device__ inline unsigned short f2bf(float f) {
  unsigned u = __float_as_uint(f);
  u += 0x7FFFu + ((u >> 16) & 1u);   // RNE to bf16
  return (unsigned short)(u >> 16);
}
__device__ inline float bf2f(unsigned short h) {
  return __uint_as_float(((unsigned)h) << 16);
}

__device__ inline void gload16(const void* g, void* l) {
  __builtin_amdgcn_global_load_lds((const __attribute__((address_space(1))) void*)g,
                                   (__attribute__((address_space(3))) void*)l, 16, 0, 0);
}

// ========== row sums of squares (numpy-pairwise, exact) + bf16 split precompute ==========
__global__ __launch_bounds__(256) void vq_rowsq(const float* __restrict__ x,
                                                const float* __restrict__ w,
                                                float* __restrict__ sx,
                                                float* __restrict__ sw,
                                                unsigned short* __restrict__ xh,
                                                unsigned short* __restrict__ xl,
                                                unsigned short* __restrict__ wh,
                                                unsigned short* __restrict__ wl) {
#pragma clang fp contract(off)
  int r = blockIdx.x * 256 + threadIdx.x;
  const float* src;
  float* dst;
  unsigned short *hdst, *ldst;
  if (r < NROWS) {
    src = x + (size_t)r * DDIM; dst = sx + r;
    hdst = xh + (size_t)r * DDIM; ldst = xl + (size_t)r * DDIM;
  } else {
    int k = r - NROWS;
    if (k >= KCODES) return;
    src = w + (size_t)k * DDIM; dst = sw + k;
    hdst = wh + (size_t)k * DDIM; ldst = wl + (size_t)k * DDIM;
  }
  // bf16 splits: v = bf2f(h) + bf2f(l) + tiny residual
  for (int i = 0; i < DDIM; i += 8) {
    float4 a = *(const float4*)&src[i];
    float4 b = *(const float4*)&src[i + 4];
    float fv[8] = {a.x, a.y, a.z, a.w, b.x, b.y, b.z, b.w};
    union { unsigned short us[8]; uint4 v; } ph, pl;
#pragma unroll
    for (int e = 0; e < 8; ++e) {
      unsigned short h = f2bf(fv[e]);
      ph.us[e] = h;
      pl.us[e] = f2bf(fv[e] - bf2f(h));   // x - bf16(x) exact in fp32
    }
    *(uint4*)&hdst[i] = ph.v;
    *(uint4*)&ldst[i] = pl.v;
  }
  // numpy pairwise_sum(256) = unrolled8(first 128) + unrolled8(second 128)
  float halves[2];
#pragma unroll
  for (int h = 0; h < 2; ++h) {
    const float* p = src + h * 128;
    float acc[8];
#pragma unroll
    for (int j = 0; j < 8; ++j) { float v = p[j]; acc[j] = v * v; }
    for (int i = 8; i < 128; i += 8) {
#pragma unroll
      for (int j = 0; j < 8; ++j) { float v = p[i + j]; float e = v * v; acc[j] = acc[j] + e; }
    }
    halves[h] = ((acc[0] + acc[1]) + (acc[2] + acc[3])) + ((acc[4] + acc[5]) + (acc[6] + acc[7]));
  }
  *dst = halves[0] + halves[1];
}

// ========== MFMA split-bf16 distance + top2 argmin ==========
#define TRM 128
#define BKM 64
#define REPAIR_T 5e-4f

__global__ __launch_bounds__(256, 2) void vq_argmin_mfma(
    const unsigned short* __restrict__ xh, const unsigned short* __restrict__ xl,
    const unsigned short* __restrict__ wh, const unsigned short* __restrict__ wl,
    const float* __restrict__ sw,
    int* __restrict__ idxOut, float* __restrict__ idxOutF,
    int* __restrict__ flagCnt, int* __restrict__ flagList) {
  __shared__ __align__(16) unsigned short lds_xh[TRM * BKM];  // 16KB each, XOR-swizzled
  __shared__ __align__(16) unsigned short lds_xl[TRM * BKM];
  __shared__ __align__(16) unsigned short lds_wh[TRM * BKM];
  __shared__ __align__(16) unsigned short lds_wl[TRM * BKM];
  __shared__ __align__(16) float sws[KCODES];
  __shared__ float mrgB1[TRM][2];
  __shared__ float mrgB2[TRM][2];
  __shared__ int   mrgI[TRM][2];

  const int t = threadIdx.x;
  const int lane = t & 63, wv = t >> 6;
  const int wr = wv >> 1, wc = wv & 1;     // wave quadrant: rows 64*wr, cols 64*wc
  const int row0 = blockIdx.x * TRM;

  { f32x4 v = ((const f32x4*)sw)[t]; ((f32x4*)sws)[t] = v; }  // 1024 floats

  const int laneRow = lane >> 3;                                  // 0..7
  const int srcswz = ((lane & 7) * 16) ^ ((laneRow & 7) << 4);    // pre-swizzled source chunk
  const char* xhB = (const char*)xh;
  const char* xlB = (const char*)xl;
  const char* whB = (const char*)wh;
  const char* wlB = (const char*)wl;

  float b1[16], b2[16];
  int bi[16];
#pragma unroll
  for (int s = 0; s < 16; ++s) { b1[s] = 3.4e38f; b2[s] = 3.4e38f; bi[s] = 0; }

  for (int ct = 0; ct < KCODES / TRM; ++ct) {
    f32x4 acc[4][4];
#pragma unroll
    for (int i = 0; i < 4; ++i)
#pragma unroll
      for (int j = 0; j < 4; ++j) acc[i][j] = (f32x4){0.f, 0.f, 0.f, 0.f};

    for (int dt = 0; dt < 4; ++dt) {
      __syncthreads();   // previous tile fully consumed
#pragma unroll
      for (int i = 0; i < 4; ++i) {
        const int rb = wv * 32 + i * 8;
        const size_t gox = (size_t)(row0 + rb + laneRow) * 512 + (size_t)(dt * 128 + srcswz);
        gload16(xhB + gox, (char*)lds_xh + rb * 128);
        gload16(xlB + gox, (char*)lds_xl + rb * 128);
        const size_t gow = (size_t)(ct * 128 + rb + laneRow) * 512 + (size_t)(dt * 128 + srcswz);
        gload16(whB + gow, (char*)lds_wh + rb * 128);
        gload16(wlB + gow, (char*)lds_wl + rb * 128);
      }
      __syncthreads();   // drains vmcnt + barrier

#pragma unroll
      for (int kh = 0; kh < 2; ++kh) {
        const int kb = kh * 64 + (lane >> 4) * 16;
        bf16x8 ah[4], al[4];
#pragma unroll
        for (int i = 0; i < 4; ++i) {
          const int r = wr * 64 + i * 16 + (lane & 15);
          const int off = r * 128 + (kb ^ ((r & 7) << 4));
          ah[i] = *(const bf16x8*)((const char*)lds_xh + off);
          al[i] = *(const bf16x8*)((const char*)lds_xl + off);
        }
#pragma unroll
        for (int j = 0; j < 4; ++j) {
          const int c = wc * 64 + j * 16 + (lane & 15);
          const int off = c * 128 + (kb ^ ((c & 7) << 4));
          bf16x8 bh = *(const bf16x8*)((const char*)lds_wh + off);
          bf16x8 bl = *(const bf16x8*)((const char*)lds_wl + off);
#pragma unroll
          for (int i = 0; i < 4; ++i) {
            acc[i][j] = __builtin_amdgcn_mfma_f32_16x16x32_bf16(ah[i], bh, acc[i][j], 0, 0, 0);
            acc[i][j] = __builtin_amdgcn_mfma_f32_16x16x32_bf16(ah[i], bl, acc[i][j], 0, 0, 0);
            acc[i][j] = __builtin_amdgcn_mfma_f32_16x16x32_bf16(al[i], bh, acc[i][j], 0, 0, 0);
          }
        }
      }
    }

    // top-2 update in e-space: e = sw - 2*dot  (sx drops out of per-row argmin)
#pragma unroll
    for (int j = 0; j < 4; ++j) {
      const int colbase = ct * 128 + wc * 64 + j * 16 + (lane & 15);
      const float swv = sws[colbase];
#pragma unroll
      for (int i = 0; i < 4; ++i)
#pragma unroll
        for (int q = 0; q < 4; ++q) {
          const int s = i * 4 + q;
          const float e = fmaf(-2.f, acc[i][j][q], swv);
          const bool c1 = e < b1[s];
          b2[s] = c1 ? b1[s] : fminf(b2[s], e);
          bi[s] = c1 ? colbase : bi[s];
          b1[s] = fminf(b1[s], e);
        }
    }
  }

  // merge across the 16 lanes sharing rows (lane&15 varies = different cols)
#pragma unroll
  for (int off = 1; off < 16; off <<= 1) {
#pragma unroll
    for (int s = 0; s < 16; ++s) {
      const float ob1 = __shfl_xor(b1[s], off);
      const float ob2 = __shfl_xor(b2[s], off);
      const int oi = __shfl_xor(bi[s], off);
      const float hi = fmaxf(b1[s], ob1);
      const bool take = ob1 < b1[s];
      b1[s] = fminf(b1[s], ob1);
      b2[s] = fminf(hi, fminf(b2[s], ob2));
      bi[s] = take ? oi : bi[s];
    }
  }
  if ((lane & 15) == 0) {
#pragma unroll
    for (int i = 0; i < 4; ++i)
#pragma unroll
      for (int q = 0; q < 4; ++q) {
        const int s = i * 4 + q;
        const int r = wr * 64 + i * 16 + (lane >> 4) * 4 + q;
        mrgB1[r][wc] = b1[s]; mrgB2[r][wc] = b2[s]; mrgI[r][wc] = bi[s];
      }
  }
  __syncthreads();
  if (t < TRM) {
    const float b1a = mrgB1[t][0], b1b = mrgB1[t][1];
    const float b2a = mrgB2[t][0], b2b = mrgB2[t][1];
    const bool take = b1b < b1a;
    const float b1f = fminf(b1a, b1b);
    const float b2f = fminf(fmaxf(b1a, b1b), fminf(b2a, b2b));
    const int idxf = take ? mrgI[t][1] : mrgI[t][0];
    const int grow = row0 + t;
    idxOut[grow] = idxf;
    idxOutF[grow] = (float)idxf;
    const bool flag = (b2f - b1f) < REPAIR_T;
    unsigned long long m = __ballot(flag);
    int base2 = 0;
    if ((t & 63) == 0) base2 = atomicAdd(flagCnt, __popcll(m));
    base2 = __shfl(base2, 0);
    if (flag) flagList[base2 + __popcll(m & ((1ull << (t & 63)) - 1ull))] = grow;
  }
}

// ========== exact repair of flagged rows (bit-exact fp32 emulation, 8 rows/block) ==========
#define RPB 8
__global__ __launch_bounds__(256) void vq_repair(const float* __restrict__ x,
                                                 const float* __restrict__ w,
                                                 const float* __restrict__ sx,
                                                 const float* __restrict__ sw,
                                                 const int* __restrict__ flagCnt,
                                                 const int* __restrict__ flagList,
                                                 int* __restrict__ idxOut,
                                                 float* __restrict__ idxOutF) {
  __shared__ float xrow[RPB][DDIM];
  __shared__ float rd[RPB][256];
  __shared__ int ri[RPB][256];
  const int t = threadIdx.x;
  const int cnt = flagCnt[0];
  for (int base = blockIdx.x * RPB; base < cnt; base += gridDim.x * RPB) {
    const int nr = min(RPB, cnt - base);
    int rowIdx[RPB];
#pragma unroll
    for (int r = 0; r < RPB; ++r)
      rowIdx[r] = flagList[base + ((r < nr) ? r : 0)];  // clamp padded slots (base < cnt)
    __syncthreads();
    for (int r = 0; r < nr; ++r)
      xrow[r][t] = x[(size_t)rowIdx[r] * DDIM + t];
    __syncthreads();
    float bD[RPB]; int bI[RPB];
#pragma unroll
    for (int r = 0; r < RPB; ++r) { bD[r] = 3.4e38f; bI[r] = 0x7fffffff; }
    for (int g = 0; g < 4; ++g) {
      const int c = g * 256 + t;
      const float4* wrp = (const float4*)(w + (size_t)c * DDIM);
      float acc[RPB];
#pragma unroll
      for (int r = 0; r < RPB; ++r) acc[r] = 0.f;
      for (int d4 = 0; d4 < DDIM / 4; ++d4) {
        const float4 wv = wrp[d4];
#pragma unroll
        for (int e = 0; e < 4; ++e) {
          const float wvx = (e == 0) ? wv.x : (e == 1) ? wv.y : (e == 2) ? wv.z : wv.w;
#pragma unroll
          for (int r = 0; r < RPB; ++r) acc[r] = fmaf(xrow[r][d4 * 4 + e], wvx, acc[r]);
        }
      }
      const float swc = sw[c];
#pragma unroll
      for (int r = 0; r < RPB; ++r) {
        // dist = fl(fl(sx+sw) - 2*dot), matching the exact path; g ascending => lowest code wins ties
        const float sxv = sx[rowIdx[r]];
        const float tt = sxv + swc;
        const float dist = tt - 2.0f * acc[r];
        if (dist < bD[r]) { bD[r] = dist; bI[r] = c; }
      }
    }
#pragma unroll
    for (int r = 0; r < RPB; ++r) { rd[r][t] = bD[r]; ri[r][t] = bI[r]; }
    __syncthreads();
    for (int s2 = 128; s2 > 0; s2 >>= 1) {
      if (t < s2) {
#pragma unroll
        for (int r = 0; r < RPB; ++r) {
          const float od = rd[r][t + s2]; const int oi = ri[r][t + s2];
          if (od < rd[r][t] || (od == rd[r][t] && oi < ri[r][t])) { rd[r][t] = od; ri[r][t] = oi; }
        }
      }
      __syncthreads();
    }
    if (t < nr) {
      const int row = rowIdx[t];
      idxOut[row] = ri[t][0];
      idxOutF[row] = (float)ri[t][0];
    }
    __syncthreads();
  }
}

// ====== gather + straight-through out + qloss partial + histogram ======
__global__ __launch_bounds__(256) void vq_quantize(const float* __restrict__ x,
                                                   const float* __restrict__ w,
                                                   const int* __restrict__ idxArr,
                                                   float* __restrict__ qout,
                                                   int* __restrict__ counts,
                                                   float* __restrict__ partialQ) {
  const int wave = threadIdx.x >> 6;
  const int lane = threadIdx.x & 63;
  const int base = blockIdx.x * 64 + wave * 16;
  float s = 0.f;
#pragma unroll 4
  for (int r = 0; r < 16; ++r) {
    const int row = base + r;
    const int idx = idxArr[row];
    float4 xv = ((const float4*)(x + (size_t)row * DDIM))[lane];
    float4 qv = ((const float4*)(w + (size_t)idx * DDIM))[lane];
    float dx = qv.x - xv.x, dy = qv.y - xv.y, dz = qv.z - xv.z, dw = qv.w - xv.w;
    float4 o;
    o.x = xv.x + dx; o.y = xv.y + dy; o.z = xv.z + dz; o.w = xv.w + dw;
    ((float4*)(qout + (size_t)row * DDIM))[lane] = o;
    s += dx * dx + dy * dy + dz * dz + dw * dw;
    if (lane == 0) atomicAdd(&counts[idx], 1);
  }
  double d = s;
  for (int off = 32; off > 0; off >>= 1) d += __shfl_down(d, off);
  __shared__ double red[4];
  if (lane == 0) red[wave] = d;
  __syncthreads();
  if (threadIdx.x == 0)
    partialQ[blockIdx.x] = (float)(red[0] + red[1] + red[2] + red[3]);
}

// ================= compactness =================
__global__ __launch_bounds__(256) void vq_compact(const float* __restrict__ w,
                                                  const float* __restrict__ sw,
                                                  float* __restrict__ partialP) {
  const int i = blockIdx.x;
  const int t = threadIdx.x;
  __shared__ float wi[DDIM];
  wi[t] = w[(size_t)i * DDIM + t];
  __syncthreads();
  float swi = sw[i];
  double s = 0.0;
  for (int j = i + 1 + t; j < KCODES; j += 256) {
    const float4* wj = (const float4*)(w + (size_t)j * DDIM);
    const float4* wi4 = (const float4*)wi;
    float acc = 0.f;
#pragma unroll 8
    for (int d4 = 0; d4 < DDIM / 4; ++d4) {
      float4 a = wi4[d4];
      float4 b = wj[d4];
      acc += a.x * b.x + a.y * b.y + a.z * b.z + a.w * b.w;
    }
    float pd2 = (swi + sw[j]) - 2.0f * acc;
    s += (double)sqrtf(fmaxf(pd2, 1e-12f));
  }
  for (int off = 32; off > 0; off >>= 1) s += __shfl_down(s, off);
  __shared__ double red[4];
  if ((t & 63) == 0) red[t >> 6] = s;
  __syncthreads();
  if (t == 0)
    partialP[i] = (float)(red[0] + red[1] + red[2] + red[3]);
}

// ========== finalize ==========
__global__ __launch_bounds__(1024) void vq_final(const float* __restrict__ partialQ,
                                                 const float* __restrict__ partialP,
                                                 const int* __restrict__ counts,
                                                 float* __restrict__ out) {
  const int t = threadIdx.x;
  const int lane = t & 63, wave = t >> 6;
  double q = (double)partialQ[t];
  double p = (double)partialP[t];
  double u = (double)fabsf((float)counts[t] - 64.0f);
  for (int off = 32; off > 0; off >>= 1) {
    q += __shfl_down(q, off);
    p += __shfl_down(p, off);
    u += __shfl_down(u, off);
  }
  __shared__ double redQ[16], redP[16], redU[16];
  if (lane == 0) { redQ[wave] = q; redP[wave] = p; redU[wave] = u; }
  __syncthreads();
  if (t == 0) {
    double sq = 0, sp = 0, su = 0;
    for (int j = 0; j < 16; ++j) { sq += redQ[j]; sp += redP[j]; su += redU[j]; }
    float m = (float)(sq / 16777216.0);
    out[ND_TOT] = m + 0.25f * m;
    out[ND_TOT + 1] = (float)(su / 1024.0);
    out[ND_TOT + 2] = (float)(2.0 * sp / 523776.0);
  }
}

extern "C" void kernel_launch(void* const* d_in, const int* in_sizes, int n_in,
                              void* d_out, int out_size, void* d_ws, size_t ws_size,
                              hipStream_t stream) {
  const float* x = (const float*)d_in[0];
  const float* w = (const float*)d_in[1];
  float* out = (float*)d_out;

  char* ws = (char*)d_ws;
  int* wsIdx    = (int*)(ws + WS_IDX);
  int* counts   = (int*)(ws + WS_COUNTS);
  float* swv    = (float*)(ws + WS_SW);
  float* sxv    = (float*)(ws + WS_SX);
  float* partQ  = (float*)(ws + WS_PARTQ);
  float* partP  = (float*)(ws + WS_PARTP);
  int* flagCnt  = (int*)(ws + WS_FLAGCNT);
  int* flagList = (int*)(ws + WS_FLAGLIST);
  unsigned short* whS = (unsigned short*)(ws + WS_WH);
  unsigned short* wlS = (unsigned short*)(ws + WS_WL);

  // bf16 splits of x live in the quantized-output region (overwritten by vq_quantize later)
  unsigned short* xhS = (unsigned short*)d_out;
  unsigned short* xlS = xhS + (size_t)ND_TOT;

  hipMemsetAsync(ws + WS_COUNTS, 0, 4096, stream);
  hipMemsetAsync(ws + WS_FLAGCNT, 0, 4, stream);

  vq_rowsq<<<(NROWS + KCODES + 255) / 256, 256, 0, stream>>>(x, w, sxv, swv, xhS, xlS, whS, wlS);
  vq_argmin_mfma<<<NROWS / TRM, 256, 0, stream>>>(xhS, xlS, whS, wlS, swv,
                                                  wsIdx, out + ND_TOT + 3, flagCnt, flagList);
  vq_repair<<<512, 256, 0, stream>>>(x, w, sxv, swv, flagCnt, flagList, wsIdx, out + ND_TOT + 3);
  vq_quantize<<<1024, 256, 0, stream>>>(x, w, wsIdx, out, counts, partQ);
  vq_compact<<<KCODES, 256, 0, stream>>>(w, swv, partP);
  vq_final<<<1, 1024, 0, stream>>>(partQ, partP, counts, out);
}

// Round 5
// 448.541 us; speedup vs baseline: 3.1868x; 1.3502x over previous
//
#include <hip/hip_runtime.h>
#include <math.h>

#define NROWS 65536
#define KCODES 1024
#define DDIM 256
#define ND_TOT (NROWS * DDIM)

// ---------- ws layout (bytes) ----------
#define WS_IDX      0         // int idx[N]          256KB
#define WS_COUNTS   262144    // int counts[K]       4KB
#define WS_SW       266240    // float sw[K]         4KB
#define WS_SX       270336    // (unused)
#define WS_PARTQ    532480    // float partQ[1024]   4KB
#define WS_PARTP    536576    // float partP[1024]   4KB
#define WS_FLAGCNT  540672    // int                 (256B slot)
#define WS_FLAGLIST 540928    // int flagList[N]     256KB
#define WS_WH       803072    // ushort wh[K*256]    512KB
#define WS_WL       1327360   // ushort wl[K*256]    512KB

typedef float f32x4 __attribute__((ext_vector_type(4)));
typedef short bf16x8 __attribute__((ext_vector_type(8)));

__device__ inline unsigned short f2bf(float f) {
  unsigned u = __float_as_uint(f);
  u += 0x7FFFu + ((u >> 16) & 1u);   // RNE to bf16
  return (unsigned short)(u >> 16);
}
__device__ inline float bf2f(unsigned short h) {
  return __uint_as_float(((unsigned)h) << 16);
}

__device__ inline void gload16(const void* g, void* l) {
  __builtin_amdgcn_global_load_lds((const __attribute__((address_space(1))) void*)g,
                                   (__attribute__((address_space(3))) void*)l, 16, 0, 0);
}

// ========== elementwise bf16 split of x (fully coalesced, grid-stride) ==========
__global__ __launch_bounds__(256) void vq_split_x(const float* __restrict__ x,
                                                  unsigned short* __restrict__ xh,
                                                  unsigned short* __restrict__ xl) {
  const size_t stride = (size_t)gridDim.x * 256;
  for (size_t i = (size_t)blockIdx.x * 256 + threadIdx.x; i < ND_TOT / 8; i += stride) {
    const size_t e = i * 8;
    float4 a = *(const float4*)&x[e];
    float4 b = *(const float4*)&x[e + 4];
    float fv[8] = {a.x, a.y, a.z, a.w, b.x, b.y, b.z, b.w};
    union { unsigned short us[8]; uint4 v; } ph, pl;
#pragma unroll
    for (int k = 0; k < 8; ++k) {
      unsigned short h = f2bf(fv[k]);
      ph.us[k] = h;
      pl.us[k] = f2bf(fv[k] - bf2f(h));   // exact in fp32
    }
    *(uint4*)&xh[e] = ph.v;
    *(uint4*)&xl[e] = pl.v;
  }
}

// ========== w prep: bf16 split + exact sw (numpy-pairwise, tiny) ==========
__global__ __launch_bounds__(256) void vq_prep_w(const float* __restrict__ w,
                                                 float* __restrict__ sw,
                                                 unsigned short* __restrict__ wh,
                                                 unsigned short* __restrict__ wl) {
#pragma clang fp contract(off)
  int k = blockIdx.x * 256 + threadIdx.x;
  if (k >= KCODES) return;
  const float* src = w + (size_t)k * DDIM;
  unsigned short* hdst = wh + (size_t)k * DDIM;
  unsigned short* ldst = wl + (size_t)k * DDIM;
  for (int i = 0; i < DDIM; i += 8) {
    float4 a = *(const float4*)&src[i];
    float4 b = *(const float4*)&src[i + 4];
    float fv[8] = {a.x, a.y, a.z, a.w, b.x, b.y, b.z, b.w};
    union { unsigned short us[8]; uint4 v; } ph, pl;
#pragma unroll
    for (int e = 0; e < 8; ++e) {
      unsigned short h = f2bf(fv[e]);
      ph.us[e] = h;
      pl.us[e] = f2bf(fv[e] - bf2f(h));
    }
    *(uint4*)&hdst[i] = ph.v;
    *(uint4*)&ldst[i] = pl.v;
  }
  float halves[2];
#pragma unroll
  for (int h = 0; h < 2; ++h) {
    const float* p = src + h * 128;
    float acc[8];
#pragma unroll
    for (int j = 0; j < 8; ++j) { float v = p[j]; acc[j] = v * v; }
    for (int i = 8; i < 128; i += 8) {
#pragma unroll
      for (int j = 0; j < 8; ++j) { float v = p[i + j]; float e = v * v; acc[j] = acc[j] + e; }
    }
    halves[h] = ((acc[0] + acc[1]) + (acc[2] + acc[3])) + ((acc[4] + acc[5]) + (acc[6] + acc[7]));
  }
  sw[k] = halves[0] + halves[1];
}

// ========== MFMA split-bf16 distance + top2 argmin ==========
#define TRM 128
#define BKM 64
#define REPAIR_T 5e-4f

__global__ __launch_bounds__(256, 2) void vq_argmin_mfma(
    const unsigned short* __restrict__ xh, const unsigned short* __restrict__ xl,
    const unsigned short* __restrict__ wh, const unsigned short* __restrict__ wl,
    const float* __restrict__ sw,
    int* __restrict__ idxOut, float* __restrict__ idxOutF,
    int* __restrict__ flagCnt, int* __restrict__ flagList) {
  __shared__ __align__(16) unsigned short lds_xh[TRM * BKM];  // 16KB each, XOR-swizzled
  __shared__ __align__(16) unsigned short lds_xl[TRM * BKM];
  __shared__ __align__(16) unsigned short lds_wh[TRM * BKM];
  __shared__ __align__(16) unsigned short lds_wl[TRM * BKM];
  __shared__ __align__(16) float sws[KCODES];
  __shared__ float mrgB1[TRM][2];
  __shared__ float mrgB2[TRM][2];
  __shared__ int   mrgI[TRM][2];

  const int t = threadIdx.x;
  const int lane = t & 63, wv = t >> 6;
  const int wr = wv >> 1, wc = wv & 1;     // wave quadrant: rows 64*wr, cols 64*wc
  const int row0 = blockIdx.x * TRM;

  { f32x4 v = ((const f32x4*)sw)[t]; ((f32x4*)sws)[t] = v; }  // 1024 floats

  const int laneRow = lane >> 3;                                  // 0..7
  const int srcswz = ((lane & 7) * 16) ^ ((laneRow & 7) << 4);    // pre-swizzled source chunk
  const char* xhB = (const char*)xh;
  const char* xlB = (const char*)xl;
  const char* whB = (const char*)wh;
  const char* wlB = (const char*)wl;

  float b1[16], b2[16];
  int bi[16];
#pragma unroll
  for (int s = 0; s < 16; ++s) { b1[s] = 3.4e38f; b2[s] = 3.4e38f; bi[s] = 0; }

  for (int ct = 0; ct < KCODES / TRM; ++ct) {
    f32x4 acc[4][4];
#pragma unroll
    for (int i = 0; i < 4; ++i)
#pragma unroll
      for (int j = 0; j < 4; ++j) acc[i][j] = (f32x4){0.f, 0.f, 0.f, 0.f};

    for (int dt = 0; dt < 4; ++dt) {
      __syncthreads();   // previous tile fully consumed
#pragma unroll
      for (int i = 0; i < 4; ++i) {
        const int rb = wv * 32 + i * 8;
        const size_t gox = (size_t)(row0 + rb + laneRow) * 512 + (size_t)(dt * 128 + srcswz);
        gload16(xhB + gox, (char*)lds_xh + rb * 128);
        gload16(xlB + gox, (char*)lds_xl + rb * 128);
        const size_t gow = (size_t)(ct * 128 + rb + laneRow) * 512 + (size_t)(dt * 128 + srcswz);
        gload16(whB + gow, (char*)lds_wh + rb * 128);
        gload16(wlB + gow, (char*)lds_wl + rb * 128);
      }
      __syncthreads();   // drains vmcnt + barrier

#pragma unroll
      for (int kh = 0; kh < 2; ++kh) {
        const int kb = kh * 64 + (lane >> 4) * 16;
        bf16x8 ah[4], al[4];
#pragma unroll
        for (int i = 0; i < 4; ++i) {
          const int r = wr * 64 + i * 16 + (lane & 15);
          const int off = r * 128 + (kb ^ ((r & 7) << 4));
          ah[i] = *(const bf16x8*)((const char*)lds_xh + off);
          al[i] = *(const bf16x8*)((const char*)lds_xl + off);
        }
#pragma unroll
        for (int j = 0; j < 4; ++j) {
          const int c = wc * 64 + j * 16 + (lane & 15);
          const int off = c * 128 + (kb ^ ((c & 7) << 4));
          bf16x8 bh = *(const bf16x8*)((const char*)lds_wh + off);
          bf16x8 bl = *(const bf16x8*)((const char*)lds_wl + off);
#pragma unroll
          for (int i = 0; i < 4; ++i) {
            acc[i][j] = __builtin_amdgcn_mfma_f32_16x16x32_bf16(ah[i], bh, acc[i][j], 0, 0, 0);
            acc[i][j] = __builtin_amdgcn_mfma_f32_16x16x32_bf16(ah[i], bl, acc[i][j], 0, 0, 0);
            acc[i][j] = __builtin_amdgcn_mfma_f32_16x16x32_bf16(al[i], bh, acc[i][j], 0, 0, 0);
          }
        }
      }
    }

    // top-2 update in e-space: e = sw - 2*dot  (sx drops out of per-row argmin)
#pragma unroll
    for (int j = 0; j < 4; ++j) {
      const int colbase = ct * 128 + wc * 64 + j * 16 + (lane & 15);
      const float swv = sws[colbase];
#pragma unroll
      for (int i = 0; i < 4; ++i)
#pragma unroll
        for (int q = 0; q < 4; ++q) {
          const int s = i * 4 + q;
          const float e = fmaf(-2.f, acc[i][j][q], swv);
          const bool c1 = e < b1[s];
          b2[s] = c1 ? b1[s] : fminf(b2[s], e);
          bi[s] = c1 ? colbase : bi[s];
          b1[s] = fminf(b1[s], e);
        }
    }
  }

  // merge across the 16 lanes sharing rows (lane&15 varies = different cols)
#pragma unroll
  for (int off = 1; off < 16; off <<= 1) {
#pragma unroll
    for (int s = 0; s < 16; ++s) {
      const float ob1 = __shfl_xor(b1[s], off);
      const float ob2 = __shfl_xor(b2[s], off);
      const int oi = __shfl_xor(bi[s], off);
      const float hi = fmaxf(b1[s], ob1);
      const bool take = ob1 < b1[s];
      b1[s] = fminf(b1[s], ob1);
      b2[s] = fminf(hi, fminf(b2[s], ob2));
      bi[s] = take ? oi : bi[s];
    }
  }
  if ((lane & 15) == 0) {
#pragma unroll
    for (int i = 0; i < 4; ++i)
#pragma unroll
      for (int q = 0; q < 4; ++q) {
        const int s = i * 4 + q;
        const int r = wr * 64 + i * 16 + (lane >> 4) * 4 + q;
        mrgB1[r][wc] = b1[s]; mrgB2[r][wc] = b2[s]; mrgI[r][wc] = bi[s];
      }
  }
  __syncthreads();
  if (t < TRM) {
    const float b1a = mrgB1[t][0], b1b = mrgB1[t][1];
    const float b2a = mrgB2[t][0], b2b = mrgB2[t][1];
    const bool take = b1b < b1a;
    const float b1f = fminf(b1a, b1b);
    const float b2f = fminf(fmaxf(b1a, b1b), fminf(b2a, b2b));
    const int idxf = take ? mrgI[t][1] : mrgI[t][0];
    const int grow = row0 + t;
    idxOut[grow] = idxf;
    idxOutF[grow] = (float)idxf;
    const bool flag = (b2f - b1f) < REPAIR_T;
    unsigned long long m = __ballot(flag);
    int base2 = 0;
    if ((t & 63) == 0) base2 = atomicAdd(flagCnt, __popcll(m));
    base2 = __shfl(base2, 0);
    if (flag) flagList[base2 + __popcll(m & ((1ull << (t & 63)) - 1ull))] = grow;
  }
}

// ========== exact repair of flagged rows (bit-exact fp32 emulation, 8 rows/block) ==========
#define RPB 8
__global__ __launch_bounds__(256) void vq_repair(const float* __restrict__ x,
                                                 const float* __restrict__ w,
                                                 const float* __restrict__ sw,
                                                 const int* __restrict__ flagCnt,
                                                 const int* __restrict__ flagList,
                                                 int* __restrict__ idxOut,
                                                 float* __restrict__ idxOutF) {
  __shared__ float xrow[RPB][DDIM];
  __shared__ float sxsh[RPB];
  __shared__ float rd[RPB][256];
  __shared__ int ri[RPB][256];
  const int t = threadIdx.x;
  const int cnt = flagCnt[0];
  for (int base = blockIdx.x * RPB; base < cnt; base += gridDim.x * RPB) {
    const int nr = min(RPB, cnt - base);
    int rowIdx[RPB];
#pragma unroll
    for (int r = 0; r < RPB; ++r)
      rowIdx[r] = flagList[base + ((r < nr) ? r : 0)];  // clamp padded slots (base < cnt)
    __syncthreads();
    for (int r = 0; r < nr; ++r)
      xrow[r][t] = x[(size_t)rowIdx[r] * DDIM + t];
    __syncthreads();
    // exact sx for this row: numpy pairwise order, no FMA
    if (t < nr) {
#pragma clang fp contract(off)
      float halves[2];
#pragma unroll
      for (int h = 0; h < 2; ++h) {
        const float* p = &xrow[t][h * 128];
        float acc[8];
#pragma unroll
        for (int j = 0; j < 8; ++j) { float v = p[j]; acc[j] = v * v; }
        for (int i = 8; i < 128; i += 8) {
#pragma unroll
          for (int j = 0; j < 8; ++j) { float v = p[i + j]; float e = v * v; acc[j] = acc[j] + e; }
        }
        halves[h] = ((acc[0] + acc[1]) + (acc[2] + acc[3])) + ((acc[4] + acc[5]) + (acc[6] + acc[7]));
      }
      sxsh[t] = halves[0] + halves[1];
    }
    __syncthreads();
    float bD[RPB]; int bI[RPB];
#pragma unroll
    for (int r = 0; r < RPB; ++r) { bD[r] = 3.4e38f; bI[r] = 0x7fffffff; }
    for (int g = 0; g < 4; ++g) {
      const int c = g * 256 + t;
      const float4* wrp = (const float4*)(w + (size_t)c * DDIM);
      float acc[RPB];
#pragma unroll
      for (int r = 0; r < RPB; ++r) acc[r] = 0.f;
      for (int d4 = 0; d4 < DDIM / 4; ++d4) {
        const float4 wv = wrp[d4];
#pragma unroll
        for (int e = 0; e < 4; ++e) {
          const float wvx = (e == 0) ? wv.x : (e == 1) ? wv.y : (e == 2) ? wv.z : wv.w;
#pragma unroll
          for (int r = 0; r < RPB; ++r) acc[r] = fmaf(xrow[r][d4 * 4 + e], wvx, acc[r]);
        }
      }
      const float swc = sw[c];
#pragma unroll
      for (int r = 0; r < RPB; ++r) {
        // dist = fl(fl(sx+sw) - 2*dot); g ascending => lowest code wins ties
        const float tt = sxsh[r] + swc;
        const float dist = tt - 2.0f * acc[r];
        if (dist < bD[r]) { bD[r] = dist; bI[r] = c; }
      }
    }
#pragma unroll
    for (int r = 0; r < RPB; ++r) { rd[r][t] = bD[r]; ri[r][t] = bI[r]; }
    __syncthreads();
    for (int s2 = 128; s2 > 0; s2 >>= 1) {
      if (t < s2) {
#pragma unroll
        for (int r = 0; r < RPB; ++r) {
          const float od = rd[r][t + s2]; const int oi = ri[r][t + s2];
          if (od < rd[r][t] || (od == rd[r][t] && oi < ri[r][t])) { rd[r][t] = od; ri[r][t] = oi; }
        }
      }
      __syncthreads();
    }
    if (t < nr) {
      const int row = rowIdx[t];
      idxOut[row] = ri[t][0];
      idxOutF[row] = (float)ri[t][0];
    }
    __syncthreads();
  }
}

// ====== gather + straight-through out + qloss partial + histogram ======
__global__ __launch_bounds__(256) void vq_quantize(const float* __restrict__ x,
                                                   const float* __restrict__ w,
                                                   const int* __restrict__ idxArr,
                                                   float* __restrict__ qout,
                                                   int* __restrict__ counts,
                                                   float* __restrict__ partialQ) {
  const int wave = threadIdx.x >> 6;
  const int lane = threadIdx.x & 63;
  const int base = blockIdx.x * 64 + wave * 16;
  float s = 0.f;
#pragma unroll 4
  for (int r = 0; r < 16; ++r) {
    const int row = base + r;
    const int idx = idxArr[row];
    float4 xv = ((const float4*)(x + (size_t)row * DDIM))[lane];
    float4 qv = ((const float4*)(w + (size_t)idx * DDIM))[lane];
    float dx = qv.x - xv.x, dy = qv.y - xv.y, dz = qv.z - xv.z, dw = qv.w - xv.w;
    float4 o;
    o.x = xv.x + dx; o.y = xv.y + dy; o.z = xv.z + dz; o.w = xv.w + dw;
    ((float4*)(qout + (size_t)row * DDIM))[lane] = o;
    s += dx * dx + dy * dy + dz * dz + dw * dw;
    if (lane == 0) atomicAdd(&counts[idx], 1);
  }
  double d = s;
  for (int off = 32; off > 0; off >>= 1) d += __shfl_down(d, off);
  __shared__ double red[4];
  if (lane == 0) red[wave] = d;
  __syncthreads();
  if (threadIdx.x == 0)
    partialQ[blockIdx.x] = (float)(red[0] + red[1] + red[2] + red[3]);
}

// ================= compactness =================
__global__ __launch_bounds__(256) void vq_compact(const float* __restrict__ w,
                                                  const float* __restrict__ sw,
                                                  float* __restrict__ partialP) {
  const int i = blockIdx.x;
  const int t = threadIdx.x;
  __shared__ float wi[DDIM];
  wi[t] = w[(size_t)i * DDIM + t];
  __syncthreads();
  float swi = sw[i];
  double s = 0.0;
  for (int j = i + 1 + t; j < KCODES; j += 256) {
    const float4* wj = (const float4*)(w + (size_t)j * DDIM);
    const float4* wi4 = (const float4*)wi;
    float acc = 0.f;
#pragma unroll 8
    for (int d4 = 0; d4 < DDIM / 4; ++d4) {
      float4 a = wi4[d4];
      float4 b = wj[d4];
      acc += a.x * b.x + a.y * b.y + a.z * b.z + a.w * b.w;
    }
    float pd2 = (swi + sw[j]) - 2.0f * acc;
    s += (double)sqrtf(fmaxf(pd2, 1e-12f));
  }
  for (int off = 32; off > 0; off >>= 1) s += __shfl_down(s, off);
  __shared__ double red[4];
  if ((t & 63) == 0) red[t >> 6] = s;
  __syncthreads();
  if (t == 0)
    partialP[i] = (float)(red[0] + red[1] + red[2] + red[3]);
}

// ========== finalize ==========
__global__ __launch_bounds__(1024) void vq_final(const float* __restrict__ partialQ,
                                                 const float* __restrict__ partialP,
                                                 const int* __restrict__ counts,
                                                 float* __restrict__ out) {
  const int t = threadIdx.x;
  const int lane = t & 63, wave = t >> 6;
  double q = (double)partialQ[t];
  double p = (double)partialP[t];
  double u = (double)fabsf((float)counts[t] - 64.0f);
  for (int off = 32; off > 0; off >>= 1) {
    q += __shfl_down(q, off);
    p += __shfl_down(p, off);
    u += __shfl_down(u, off);
  }
  __shared__ double redQ[16], redP[16], redU[16];
  if (lane == 0) { redQ[wave] = q; redP[wave] = p; redU[wave] = u; }
  __syncthreads();
  if (t == 0) {
    double sq = 0, sp = 0, su = 0;
    for (int j = 0; j < 16; ++j) { sq += redQ[j]; sp += redP[j]; su += redU[j]; }
    float m = (float)(sq / 16777216.0);
    out[ND_TOT] = m + 0.25f * m;
    out[ND_TOT + 1] = (float)(su / 1024.0);
    out[ND_TOT + 2] = (float)(2.0 * sp / 523776.0);
  }
}

extern "C" void kernel_launch(void* const* d_in, const int* in_sizes, int n_in,
                              void* d_out, int out_size, void* d_ws, size_t ws_size,
                              hipStream_t stream) {
  const float* x = (const float*)d_in[0];
  const float* w = (const float*)d_in[1];
  float* out = (float*)d_out;

  char* ws = (char*)d_ws;
  int* wsIdx    = (int*)(ws + WS_IDX);
  int* counts   = (int*)(ws + WS_COUNTS);
  float* swv    = (float*)(ws + WS_SW);
  float* partQ  = (float*)(ws + WS_PARTQ);
  float* partP  = (float*)(ws + WS_PARTP);
  int* flagCnt  = (int*)(ws + WS_FLAGCNT);
  int* flagList = (int*)(ws + WS_FLAGLIST);
  unsigned short* whS = (unsigned short*)(ws + WS_WH);
  unsigned short* wlS = (unsigned short*)(ws + WS_WL);

  // bf16 splits of x live in the quantized-output region (overwritten by vq_quantize later)
  unsigned short* xhS = (unsigned short*)d_out;
  unsigned short* xlS = xhS + (size_t)ND_TOT;

  hipMemsetAsync(ws + WS_COUNTS, 0, 4096, stream);
  hipMemsetAsync(ws + WS_FLAGCNT, 0, 4, stream);

  vq_split_x<<<2048, 256, 0, stream>>>(x, xhS, xlS);
  vq_prep_w<<<4, 256, 0, stream>>>(w, swv, whS, wlS);
  vq_argmin_mfma<<<NROWS / TRM, 256, 0, stream>>>(xhS, xlS, whS, wlS, swv,
                                                  wsIdx, out + ND_TOT + 3, flagCnt, flagList);
  vq_repair<<<512, 256, 0, stream>>>(x, w, swv, flagCnt, flagList, wsIdx, out + ND_TOT + 3);
  vq_quantize<<<1024, 256, 0, stream>>>(x, w, wsIdx, out, counts, partQ);
  vq_compact<<<KCODES, 256, 0, stream>>>(w, swv, partP);
  vq_final<<<1, 1024, 0, stream>>>(partQ, partP, counts, out);
}

// Round 6
// 374.981 us; speedup vs baseline: 3.8119x; 1.1962x over previous
//
#include <hip/hip_runtime.h>
#include <math.h>

#define NROWS 65536
#define KCODES 1024
#define DDIM 256
#define ND_TOT (NROWS * DDIM)

// ---------- ws layout (bytes) ----------
#define WS_IDX      0         // int idx[N]          256KB
#define WS_COUNTS   262144    // int counts[K]       4KB
#define WS_SW       266240    // float sw[K]         4KB
#define WS_PARTQ    532480    // float partQ[1024]   4KB
#define WS_PARTP    536576    // float partP[1024]   4KB
#define WS_FLAGCNT  540672    // int                 (256B slot)
#define WS_FLAGLIST 540928    // int flagList[N]     256KB
#define WS_WH       803072    // ushort wh[K*256]    512KB
#define WS_WL       1327360   // ushort wl[K*256]    512KB

typedef float f32x4 __attribute__((ext_vector_type(4)));
typedef short bf16x8 __attribute__((ext_vector_type(8)));

__device__ inline unsigned short f2bf(float f) {
  unsigned u = __float_as_uint(f);
  u += 0x7FFFu + ((u >> 16) & 1u);   // RNE to bf16
  return (unsigned short)(u >> 16);
}
__device__ inline float bf2f(unsigned short h) {
  return __uint_as_float(((unsigned)h) << 16);
}

__device__ inline void gload16(const void* g, void* l) {
  __builtin_amdgcn_global_load_lds((const __attribute__((address_space(1))) void*)g,
                                   (__attribute__((address_space(3))) void*)l, 16, 0, 0);
}

// ========== elementwise bf16 split of x (fully coalesced, grid-stride) ==========
__global__ __launch_bounds__(256) void vq_split_x(const float* __restrict__ x,
                                                  unsigned short* __restrict__ xh,
                                                  unsigned short* __restrict__ xl) {
  const size_t stride = (size_t)gridDim.x * 256;
  for (size_t i = (size_t)blockIdx.x * 256 + threadIdx.x; i < ND_TOT / 8; i += stride) {
    const size_t e = i * 8;
    float4 a = *(const float4*)&x[e];
    float4 b = *(const float4*)&x[e + 4];
    float fv[8] = {a.x, a.y, a.z, a.w, b.x, b.y, b.z, b.w};
    union { unsigned short us[8]; uint4 v; } ph, pl;
#pragma unroll
    for (int k = 0; k < 8; ++k) {
      unsigned short h = f2bf(fv[k]);
      ph.us[k] = h;
      pl.us[k] = f2bf(fv[k] - bf2f(h));   // exact in fp32
    }
    *(uint4*)&xh[e] = ph.v;
    *(uint4*)&xl[e] = pl.v;
  }
}

// ========== w prep: bf16 split + exact sw (numpy-pairwise, tiny) ==========
__global__ __launch_bounds__(256) void vq_prep_w(const float* __restrict__ w,
                                                 float* __restrict__ sw,
                                                 unsigned short* __restrict__ wh,
                                                 unsigned short* __restrict__ wl) {
#pragma clang fp contract(off)
  int k = blockIdx.x * 256 + threadIdx.x;
  if (k >= KCODES) return;
  const float* src = w + (size_t)k * DDIM;
  unsigned short* hdst = wh + (size_t)k * DDIM;
  unsigned short* ldst = wl + (size_t)k * DDIM;
  for (int i = 0; i < DDIM; i += 8) {
    float4 a = *(const float4*)&src[i];
    float4 b = *(const float4*)&src[i + 4];
    float fv[8] = {a.x, a.y, a.z, a.w, b.x, b.y, b.z, b.w};
    union { unsigned short us[8]; uint4 v; } ph, pl;
#pragma unroll
    for (int e = 0; e < 8; ++e) {
      unsigned short h = f2bf(fv[e]);
      ph.us[e] = h;
      pl.us[e] = f2bf(fv[e] - bf2f(h));
    }
    *(uint4*)&hdst[i] = ph.v;
    *(uint4*)&ldst[i] = pl.v;
  }
  float halves[2];
#pragma unroll
  for (int h = 0; h < 2; ++h) {
    const float* p = src + h * 128;
    float acc[8];
#pragma unroll
    for (int j = 0; j < 8; ++j) { float v = p[j]; acc[j] = v * v; }
    for (int i = 8; i < 128; i += 8) {
#pragma unroll
      for (int j = 0; j < 8; ++j) { float v = p[i + j]; float e = v * v; acc[j] = acc[j] + e; }
    }
    halves[h] = ((acc[0] + acc[1]) + (acc[2] + acc[3])) + ((acc[4] + acc[5]) + (acc[6] + acc[7]));
  }
  sw[k] = halves[0] + halves[1];
}

// ========== MFMA split-bf16 distance + top2 argmin ==========
#define TRM 128
#define BKM 64
// Flag threshold: hard bound for a reference-order flip is
//   approx-e error (<=~6e-6: missing xl*wl + split residuals + MFMA accum)
// + reference rounding reorder width (~6.1e-5 = 2*(ulp(256)/2 + ulp(256)/2)).
// Total ~7.3e-5; T=1.5e-4 keeps 2x margin. (R5: T=5e-4 flagged ~35% of rows.)
#define REPAIR_T 1.5e-4f

__global__ __launch_bounds__(256, 2) void vq_argmin_mfma(
    const unsigned short* __restrict__ xh, const unsigned short* __restrict__ xl,
    const unsigned short* __restrict__ wh, const unsigned short* __restrict__ wl,
    const float* __restrict__ sw,
    int* __restrict__ idxOut, float* __restrict__ idxOutF,
    int* __restrict__ flagCnt, int* __restrict__ flagList) {
  __shared__ __align__(16) unsigned short lds_xh[TRM * BKM];  // 16KB each, XOR-swizzled
  __shared__ __align__(16) unsigned short lds_xl[TRM * BKM];
  __shared__ __align__(16) unsigned short lds_wh[TRM * BKM];
  __shared__ __align__(16) unsigned short lds_wl[TRM * BKM];
  __shared__ __align__(16) float sws[KCODES];
  __shared__ float mrgB1[TRM][2];
  __shared__ float mrgB2[TRM][2];
  __shared__ int   mrgI[TRM][2];

  const int t = threadIdx.x;
  const int lane = t & 63, wv = t >> 6;
  const int wr = wv >> 1, wc = wv & 1;     // wave quadrant: rows 64*wr, cols 64*wc
  const int row0 = blockIdx.x * TRM;

  { f32x4 v = ((const f32x4*)sw)[t]; ((f32x4*)sws)[t] = v; }  // 1024 floats

  const int laneRow = lane >> 3;                                  // 0..7
  const int srcswz = ((lane & 7) * 16) ^ ((laneRow & 7) << 4);    // pre-swizzled source chunk
  const char* xhB = (const char*)xh;
  const char* xlB = (const char*)xl;
  const char* whB = (const char*)wh;
  const char* wlB = (const char*)wl;

  float b1[16], b2[16];
  int bi[16];
#pragma unroll
  for (int s = 0; s < 16; ++s) { b1[s] = 3.4e38f; b2[s] = 3.4e38f; bi[s] = 0; }

  for (int ct = 0; ct < KCODES / TRM; ++ct) {
    f32x4 acc[4][4];
#pragma unroll
    for (int i = 0; i < 4; ++i)
#pragma unroll
      for (int j = 0; j < 4; ++j) acc[i][j] = (f32x4){0.f, 0.f, 0.f, 0.f};

    for (int dt = 0; dt < 4; ++dt) {
      __syncthreads();   // previous tile fully consumed
#pragma unroll
      for (int i = 0; i < 4; ++i) {
        const int rb = wv * 32 + i * 8;
        const size_t gox = (size_t)(row0 + rb + laneRow) * 512 + (size_t)(dt * 128 + srcswz);
        gload16(xhB + gox, (char*)lds_xh + rb * 128);
        gload16(xlB + gox, (char*)lds_xl + rb * 128);
        const size_t gow = (size_t)(ct * 128 + rb + laneRow) * 512 + (size_t)(dt * 128 + srcswz);
        gload16(whB + gow, (char*)lds_wh + rb * 128);
        gload16(wlB + gow, (char*)lds_wl + rb * 128);
      }
      __syncthreads();   // drains vmcnt + barrier

#pragma unroll
      for (int kh = 0; kh < 2; ++kh) {
        const int kb = kh * 64 + (lane >> 4) * 16;
        bf16x8 ah[4], al[4];
#pragma unroll
        for (int i = 0; i < 4; ++i) {
          const int r = wr * 64 + i * 16 + (lane & 15);
          const int off = r * 128 + (kb ^ ((r & 7) << 4));
          ah[i] = *(const bf16x8*)((const char*)lds_xh + off);
          al[i] = *(const bf16x8*)((const char*)lds_xl + off);
        }
#pragma unroll
        for (int j = 0; j < 4; ++j) {
          const int c = wc * 64 + j * 16 + (lane & 15);
          const int off = c * 128 + (kb ^ ((c & 7) << 4));
          bf16x8 bh = *(const bf16x8*)((const char*)lds_wh + off);
          bf16x8 bl = *(const bf16x8*)((const char*)lds_wl + off);
#pragma unroll
          for (int i = 0; i < 4; ++i) {
            acc[i][j] = __builtin_amdgcn_mfma_f32_16x16x32_bf16(ah[i], bh, acc[i][j], 0, 0, 0);
            acc[i][j] = __builtin_amdgcn_mfma_f32_16x16x32_bf16(ah[i], bl, acc[i][j], 0, 0, 0);
            acc[i][j] = __builtin_amdgcn_mfma_f32_16x16x32_bf16(al[i], bh, acc[i][j], 0, 0, 0);
          }
        }
      }
    }

    // top-2 update in e-space: e = sw - 2*dot  (sx drops out of per-row argmin)
#pragma unroll
    for (int j = 0; j < 4; ++j) {
      const int colbase = ct * 128 + wc * 64 + j * 16 + (lane & 15);
      const float swv = sws[colbase];
#pragma unroll
      for (int i = 0; i < 4; ++i)
#pragma unroll
        for (int q = 0; q < 4; ++q) {
          const int s = i * 4 + q;
          const float e = fmaf(-2.f, acc[i][j][q], swv);
          const bool c1 = e < b1[s];
          b2[s] = c1 ? b1[s] : fminf(b2[s], e);
          bi[s] = c1 ? colbase : bi[s];
          b1[s] = fminf(b1[s], e);
        }
    }
  }

  // merge across the 16 lanes sharing rows (lane&15 varies = different cols)
#pragma unroll
  for (int off = 1; off < 16; off <<= 1) {
#pragma unroll
    for (int s = 0; s < 16; ++s) {
      const float ob1 = __shfl_xor(b1[s], off);
      const float ob2 = __shfl_xor(b2[s], off);
      const int oi = __shfl_xor(bi[s], off);
      const float hi = fmaxf(b1[s], ob1);
      const bool take = ob1 < b1[s];
      b1[s] = fminf(b1[s], ob1);
      b2[s] = fminf(hi, fminf(b2[s], ob2));
      bi[s] = take ? oi : bi[s];
    }
  }
  if ((lane & 15) == 0) {
#pragma unroll
    for (int i = 0; i < 4; ++i)
#pragma unroll
      for (int q = 0; q < 4; ++q) {
        const int s = i * 4 + q;
        const int r = wr * 64 + i * 16 + (lane >> 4) * 4 + q;
        mrgB1[r][wc] = b1[s]; mrgB2[r][wc] = b2[s]; mrgI[r][wc] = bi[s];
      }
  }
  __syncthreads();
  if (t < TRM) {
    const float b1a = mrgB1[t][0], b1b = mrgB1[t][1];
    const float b2a = mrgB2[t][0], b2b = mrgB2[t][1];
    const bool take = b1b < b1a;
    const float b1f = fminf(b1a, b1b);
    const float b2f = fminf(fmaxf(b1a, b1b), fminf(b2a, b2b));
    const int idxf = take ? mrgI[t][1] : mrgI[t][0];
    const int grow = row0 + t;
    idxOut[grow] = idxf;
    idxOutF[grow] = (float)idxf;
    const bool flag = (b2f - b1f) < REPAIR_T;
    unsigned long long m = __ballot(flag);
    int base2 = 0;
    if ((t & 63) == 0) base2 = atomicAdd(flagCnt, __popcll(m));
    base2 = __shfl(base2, 0);
    if (flag) flagList[base2 + __popcll(m & ((1ull << (t & 63)) - 1ull))] = grow;
  }
}

// ========== exact repair of flagged rows (bit-exact fp32 emulation, 8 rows/block) ==========
#define RPB 8
__global__ __launch_bounds__(256) void vq_repair(const float* __restrict__ x,
                                                 const float* __restrict__ w,
                                                 const float* __restrict__ sw,
                                                 const int* __restrict__ flagCnt,
                                                 const int* __restrict__ flagList,
                                                 int* __restrict__ idxOut,
                                                 float* __restrict__ idxOutF) {
  __shared__ float xrow[RPB][DDIM];
  __shared__ float sxsh[RPB];
  __shared__ float rd[RPB][256];
  __shared__ int ri[RPB][256];
  const int t = threadIdx.x;
  const int cnt = flagCnt[0];
  for (int base = blockIdx.x * RPB; base < cnt; base += gridDim.x * RPB) {
    const int nr = min(RPB, cnt - base);
    int rowIdx[RPB];
#pragma unroll
    for (int r = 0; r < RPB; ++r)
      rowIdx[r] = flagList[base + ((r < nr) ? r : 0)];  // clamp padded slots (base < cnt)
    __syncthreads();
    for (int r = 0; r < nr; ++r)
      xrow[r][t] = x[(size_t)rowIdx[r] * DDIM + t];
    __syncthreads();
    // exact sx for this row: numpy pairwise order, no FMA
    if (t < nr) {
#pragma clang fp contract(off)
      float halves[2];
#pragma unroll
      for (int h = 0; h < 2; ++h) {
        const float* p = &xrow[t][h * 128];
        float acc[8];
#pragma unroll
        for (int j = 0; j < 8; ++j) { float v = p[j]; acc[j] = v * v; }
        for (int i = 8; i < 128; i += 8) {
#pragma unroll
          for (int j = 0; j < 8; ++j) { float v = p[i + j]; float e = v * v; acc[j] = acc[j] + e; }
        }
        halves[h] = ((acc[0] + acc[1]) + (acc[2] + acc[3])) + ((acc[4] + acc[5]) + (acc[6] + acc[7]));
      }
      sxsh[t] = halves[0] + halves[1];
    }
    __syncthreads();
    float bD[RPB]; int bI[RPB];
#pragma unroll
    for (int r = 0; r < RPB; ++r) { bD[r] = 3.4e38f; bI[r] = 0x7fffffff; }
    for (int g = 0; g < 4; ++g) {
      const int c = g * 256 + t;
      const float4* wrp = (const float4*)(w + (size_t)c * DDIM);
      float acc[RPB];
#pragma unroll
      for (int r = 0; r < RPB; ++r) acc[r] = 0.f;
      for (int d4 = 0; d4 < DDIM / 4; ++d4) {
        const float4 wv = wrp[d4];
#pragma unroll
        for (int e = 0; e < 4; ++e) {
          const float wvx = (e == 0) ? wv.x : (e == 1) ? wv.y : (e == 2) ? wv.z : wv.w;
#pragma unroll
          for (int r = 0; r < RPB; ++r) acc[r] = fmaf(xrow[r][d4 * 4 + e], wvx, acc[r]);
        }
      }
      const float swc = sw[c];
#pragma unroll
      for (int r = 0; r < RPB; ++r) {
        // dist = fl(fl(sx+sw) - 2*dot); g ascending => lowest code wins ties
        const float tt = sxsh[r] + swc;
        const float dist = tt - 2.0f * acc[r];
        if (dist < bD[r]) { bD[r] = dist; bI[r] = c; }
      }
    }
#pragma unroll
    for (int r = 0; r < RPB; ++r) { rd[r][t] = bD[r]; ri[r][t] = bI[r]; }
    __syncthreads();
    for (int s2 = 128; s2 > 0; s2 >>= 1) {
      if (t < s2) {
#pragma unroll
        for (int r = 0; r < RPB; ++r) {
          const float od = rd[r][t + s2]; const int oi = ri[r][t + s2];
          if (od < rd[r][t] || (od == rd[r][t] && oi < ri[r][t])) { rd[r][t] = od; ri[r][t] = oi; }
        }
      }
      __syncthreads();
    }
    if (t < nr) {
      const int row = rowIdx[t];
      idxOut[row] = ri[t][0];
      idxOutF[row] = (float)ri[t][0];
    }
    __syncthreads();
  }
}

// ====== gather + straight-through out + qloss partial + histogram ======
__global__ __launch_bounds__(256) void vq_quantize(const float* __restrict__ x,
                                                   const float* __restrict__ w,
                                                   const int* __restrict__ idxArr,
                                                   float* __restrict__ qout,
                                                   int* __restrict__ counts,
                                                   float* __restrict__ partialQ) {
  const int wave = threadIdx.x >> 6;
  const int lane = threadIdx.x & 63;
  const int base = blockIdx.x * 64 + wave * 16;
  float s = 0.f;
#pragma unroll 4
  for (int r = 0; r < 16; ++r) {
    const int row = base + r;
    const int idx = idxArr[row];
    float4 xv = ((const float4*)(x + (size_t)row * DDIM))[lane];
    float4 qv = ((const float4*)(w + (size_t)idx * DDIM))[lane];
    float dx = qv.x - xv.x, dy = qv.y - xv.y, dz = qv.z - xv.z, dw = qv.w - xv.w;
    float4 o;
    o.x = xv.x + dx; o.y = xv.y + dy; o.z = xv.z + dz; o.w = xv.w + dw;
    ((float4*)(qout + (size_t)row * DDIM))[lane] = o;
    s += dx * dx + dy * dy + dz * dz + dw * dw;
    if (lane == 0) atomicAdd(&counts[idx], 1);
  }
  double d = s;
  for (int off = 32; off > 0; off >>= 1) d += __shfl_down(d, off);
  __shared__ double red[4];
  if (lane == 0) red[wave] = d;
  __syncthreads();
  if (threadIdx.x == 0)
    partialQ[blockIdx.x] = (float)(red[0] + red[1] + red[2] + red[3]);
}

// ================= compactness =================
__global__ __launch_bounds__(256) void vq_compact(const float* __restrict__ w,
                                                  const float* __restrict__ sw,
                                                  float* __restrict__ partialP) {
  const int i = blockIdx.x;
  const int t = threadIdx.x;
  __shared__ float wi[DDIM];
  wi[t] = w[(size_t)i * DDIM + t];
  __syncthreads();
  float swi = sw[i];
  double s = 0.0;
  for (int j = i + 1 + t; j < KCODES; j += 256) {
    const float4* wj = (const float4*)(w + (size_t)j * DDIM);
    const float4* wi4 = (const float4*)wi;
    float acc = 0.f;
#pragma unroll 8
    for (int d4 = 0; d4 < DDIM / 4; ++d4) {
      float4 a = wi4[d4];
      float4 b = wj[d4];
      acc += a.x * b.x + a.y * b.y + a.z * b.z + a.w * b.w;
    }
    float pd2 = (swi + sw[j]) - 2.0f * acc;
    s += (double)sqrtf(fmaxf(pd2, 1e-12f));
  }
  for (int off = 32; off > 0; off >>= 1) s += __shfl_down(s, off);
  __shared__ double red[4];
  if ((t & 63) == 0) red[t >> 6] = s;
  __syncthreads();
  if (t == 0)
    partialP[i] = (float)(red[0] + red[1] + red[2] + red[3]);
}

// ========== finalize ==========
__global__ __launch_bounds__(1024) void vq_final(const float* __restrict__ partialQ,
                                                 const float* __restrict__ partialP,
                                                 const int* __restrict__ counts,
                                                 float* __restrict__ out) {
  const int t = threadIdx.x;
  const int lane = t & 63, wave = t >> 6;
  double q = (double)partialQ[t];
  double p = (double)partialP[t];
  double u = (double)fabsf((float)counts[t] - 64.0f);
  for (int off = 32; off > 0; off >>= 1) {
    q += __shfl_down(q, off);
    p += __shfl_down(p, off);
    u += __shfl_down(u, off);
  }
  __shared__ double redQ[16], redP[16], redU[16];
  if (lane == 0) { redQ[wave] = q; redP[wave] = p; redU[wave] = u; }
  __syncthreads();
  if (t == 0) {
    double sq = 0, sp = 0, su = 0;
    for (int j = 0; j < 16; ++j) { sq += redQ[j]; sp += redP[j]; su += redU[j]; }
    float m = (float)(sq / 16777216.0);
    out[ND_TOT] = m + 0.25f * m;
    out[ND_TOT + 1] = (float)(su / 1024.0);
    out[ND_TOT + 2] = (float)(2.0 * sp / 523776.0);
  }
}

extern "C" void kernel_launch(void* const* d_in, const int* in_sizes, int n_in,
                              void* d_out, int out_size, void* d_ws, size_t ws_size,
                              hipStream_t stream) {
  const float* x = (const float*)d_in[0];
  const float* w = (const float*)d_in[1];
  float* out = (float*)d_out;

  char* ws = (char*)d_ws;
  int* wsIdx    = (int*)(ws + WS_IDX);
  int* counts   = (int*)(ws + WS_COUNTS);
  float* swv    = (float*)(ws + WS_SW);
  float* partQ  = (float*)(ws + WS_PARTQ);
  float* partP  = (float*)(ws + WS_PARTP);
  int* flagCnt  = (int*)(ws + WS_FLAGCNT);
  int* flagList = (int*)(ws + WS_FLAGLIST);
  unsigned short* whS = (unsigned short*)(ws + WS_WH);
  unsigned short* wlS = (unsigned short*)(ws + WS_WL);

  // bf16 splits of x live in the quantized-output region (overwritten by vq_quantize later)
  unsigned short* xhS = (unsigned short*)d_out;
  unsigned short* xlS = xhS + (size_t)ND_TOT;

  hipMemsetAsync(ws + WS_COUNTS, 0, 4096, stream);
  hipMemsetAsync(ws + WS_FLAGCNT, 0, 4, stream);

  vq_split_x<<<2048, 256, 0, stream>>>(x, xhS, xlS);
  vq_prep_w<<<4, 256, 0, stream>>>(w, swv, whS, wlS);
  vq_argmin_mfma<<<NROWS / TRM, 256, 0, stream>>>(xhS, xlS, whS, wlS, swv,
                                                  wsIdx, out + ND_TOT + 3, flagCnt, flagList);
  vq_repair<<<1024, 256, 0, stream>>>(x, w, swv, flagCnt, flagList, wsIdx, out + ND_TOT + 3);
  vq_quantize<<<1024, 256, 0, stream>>>(x, w, wsIdx, out, counts, partQ);
  vq_compact<<<KCODES, 256, 0, stream>>>(w, swv, partP);
  vq_final<<<1, 1024, 0, stream>>>(partQ, partP, counts, out);
}